// Round 14
// baseline (99.301 us; speedup 1.0000x reference)
//
#include <hip/hip_runtime.h>
#include <stdint.h>

#define S_LEN 2048
#define EMB 1024

typedef __bf16 bf16x8 __attribute__((ext_vector_type(8)));
typedef __bf16 bf16x4 __attribute__((ext_vector_type(4)));
typedef float f32x4 __attribute__((ext_vector_type(4)));

__device__ __forceinline__ unsigned short f2bf(float f) {
  unsigned int b = __float_as_uint(f);
  b += 0x7FFFu + ((b >> 16) & 1u);
  return (unsigned short)(b >> 16);
}

__device__ __forceinline__ bf16x4 c4(float4 a) {
  bf16x4 r;
  r[0] = (__bf16)a.x; r[1] = (__bf16)a.y; r[2] = (__bf16)a.z; r[3] = (__bf16)a.w;
  return r;
}

#define GLD16(gp, lp)                                                          \
  __builtin_amdgcn_global_load_lds(                                            \
      (const __attribute__((address_space(1))) void*)(gp),                     \
      (__attribute__((address_space(3))) void*)(lp), 16, 0, 0)

// row-local swizzle for 2KB bf16 rows: XOR row bits 7-9 into bank bits 4-6
__device__ __forceinline__ int swz(int L) {
  return L ^ (((L >> 7) & 7) << 4);
}

// ---------------------------------------------------------------------------
// Kernel 1: per-(n,s) 16x16 head-Gram attention, v13 combined:
// line-optimal contiguous reads + reg-staged double-buffered pipeline with
// loads in flight under ALL-wave compute. Block = 16 positions, 4 steps x
// (4 positions, one per wave). Compute mechanics = R5-verified.
// ---------------------------------------------------------------------------
__global__ __launch_bounds__(256) void attn_kernel(
    const float* __restrict__ Q, const float* __restrict__ K,
    const float* __restrict__ V, const int* __restrict__ mask,
    __bf16* __restrict__ X) {
  __shared__ __bf16 Qb[2][4][1024];  // [buf][pos-slot][elem], swizzled rows
  __shared__ __bf16 Kb[2][4][1024];  // swizzled rows
  __shared__ __bf16 Vb[2][4][1024];  // linear rows
  __shared__ __bf16 As[4][16][16];   // per-wave attention tile

  const int t = threadIdx.x;
  const int lane = t & 63;
  const int wv = t >> 6;
  const int pos0 = blockIdx.x * 16;
  const int n = pos0 >> 11;  // uniform in block (16 | 2048)
  const int col = lane & 15;
  const int grp = lane >> 4;
  const int gc = grp & 1;

  const int4 mrow = *(const int4*)(mask + col * 16 + grp * 4);

  const int Lw = 8 * t;          // byte offset of this thread's 4 elems
  const int LwS = swz(Lw);

  float4 fq[4], fk[4], fv[4];    // in-flight registers (next step, 48 VGPR)

  // issue 12 perfectly-contiguous 1KB float4 loads (4 positions x Q,K,V)
  auto ISSUE = [&](int step) {
#pragma unroll
    for (int p = 0; p < 4; ++p) {
      const size_t base = (size_t)(pos0 + step * 4 + p) * EMB + t * 4;
      fq[p] = *(const float4*)(Q + base);
      fk[p] = *(const float4*)(K + base);
      fv[p] = *(const float4*)(V + base);
    }
  };
  // cvt fp32->bf16 and place into LDS buffer `buf`
  auto WRITE = [&](int buf) {
#pragma unroll
    for (int p = 0; p < 4; ++p) {
      *(bf16x4*)((char*)&Qb[buf][p][0] + LwS) = c4(fq[p]);
      *(bf16x4*)((char*)&Kb[buf][p][0] + LwS) = c4(fk[p]);
      *(bf16x4*)((char*)&Vb[buf][p][0] + Lw) = c4(fv[p]);
    }
  };

  // R5-verified compute for position slot wv of buffer `buf`
  auto COMPUTE = [&](int buf, int step) {
    const int pos = pos0 + step * 4 + wv;
    const int s = pos & 2047;
    const __bf16* qr = &Qb[buf][wv][0];
    const __bf16* kr = &Kb[buf][wv][0];
    const __bf16* vr = &Vb[buf][wv][0];

    // QK^T fragments: elems col*64 + {0,32} + grp*8 .. +7
    const int L0 = col * 128 + grp * 16;
    const int L1 = L0 + 64;
    const bf16x8 qa0 = *(const bf16x8*)((const char*)qr + swz(L0));
    const bf16x8 qa1 = *(const bf16x8*)((const char*)qr + swz(L1));
    const bf16x8 kb0 = *(const bf16x8*)((const char*)kr + swz(L0));
    const bf16x8 kb1 = *(const bf16x8*)((const char*)kr + swz(L1));

    // E^T = K.Q^T (swapped): lane holds E[j=grp*4+r][i=col]
    f32x4 en = {0.f, 0.f, 0.f, 0.f};
    en = __builtin_amdgcn_mfma_f32_16x16x32_bf16(kb0, qa0, en, 0, 0, 0);
    en = __builtin_amdgcn_mfma_f32_16x16x32_bf16(kb1, qa1, en, 0, 0, 0);

    // mask + softmax over j
    float p[4];
    p[0] = (mrow.x == 0) ? -1e30f : en[0] * 0.125f;
    p[1] = (mrow.y == 0) ? -1e30f : en[1] * 0.125f;
    p[2] = (mrow.z == 0) ? -1e30f : en[2] * 0.125f;
    p[3] = (mrow.w == 0) ? -1e30f : en[3] * 0.125f;
    float mx = fmaxf(fmaxf(p[0], p[1]), fmaxf(p[2], p[3]));
    mx = fmaxf(mx, __shfl_xor(mx, 16));
    mx = fmaxf(mx, __shfl_xor(mx, 32));
    float ex[4], sm = 0.f;
#pragma unroll
    for (int r = 0; r < 4; ++r) {
      ex[r] = __expf(p[r] - mx);
      sm += ex[r];
    }
    sm += __shfl_xor(sm, 16);
    sm += __shfl_xor(sm, 32);
    const float inv = __builtin_amdgcn_rcpf(sm);
    bf16x4 aw;
#pragma unroll
    for (int r = 0; r < 4; ++r) aw[r] = (__bf16)(ex[r] * inv);
    *(bf16x4*)&As[wv][col][grp * 4] = aw;  // A[col][grp*4+r]

    // pa[e] = A[col][grp*8+e] for grp<2; zero-pad k>=16
    const bf16x8 pt = *(const bf16x8*)&As[wv][col][gc * 8];
    bf16x8 pa;
#pragma unroll
    for (int e = 0; e < 8; ++e) pa[e] = (grp < 2) ? pt[e] : (__bf16)0.f;

    // PV + direct stores
    const size_t xrow = (size_t)n * S_LEN + (size_t)col * 128 + (s >> 4);
    __bf16* xp = X + xrow * EMB + (size_t)((s & 15) * 64 + grp * 4);
#pragma unroll
    for (int c = 0; c < 4; ++c) {
      bf16x8 vf;
#pragma unroll
      for (int e = 0; e < 8; ++e)
        vf[e] = vr[(gc * 8 + e) * 64 + c * 16 + col];
      f32x4 o = {0.f, 0.f, 0.f, 0.f};
      o = __builtin_amdgcn_mfma_f32_16x16x32_bf16(vf, pa, o, 0, 0, 0);
      bf16x4 w;
#pragma unroll
      for (int r = 0; r < 4; ++r) w[r] = (__bf16)o[r];
      *(bf16x4*)(xp + c * 16) = w;
    }
  };

  // ---- pipelined main loop ----
  ISSUE(0);
  WRITE(0);
  __syncthreads();
#pragma unroll
  for (int step = 0; step < 4; ++step) {
    const int buf = step & 1;
    if (step < 3) {
      ISSUE(step + 1);
      __builtin_amdgcn_sched_barrier(0);  // pin load issue above compute
    }
    COMPUTE(buf, step);
    if (step < 3) WRITE(buf ^ 1);  // vmcnt drains here, after compute
    __syncthreads();
  }
}

// ---------------------------------------------------------------------------
// Kernel 2: W_out fp32 -> bf16 bits
// ---------------------------------------------------------------------------
__global__ __launch_bounds__(256) void wconv_kernel(
    const float* __restrict__ W, unsigned short* __restrict__ Wb) {
  const int idx = blockIdx.x * 256 + threadIdx.x;
  float4 w = *(const float4*)(W + (size_t)idx * 4);
  ushort4 o;
  o.x = f2bf(w.x);
  o.y = f2bf(w.y);
  o.z = f2bf(w.z);
  o.w = f2bf(w.w);
  *(ushort4*)(Wb + (size_t)idx * 4) = o;
}

// ---------------------------------------------------------------------------
// Kernel 3: C[16384][1024] = X[16384][1024] * W[1024][1024]^T + bias
// ---------------------------------------------------------------------------
__global__ __launch_bounds__(256) void gemm_kernel(
    const unsigned short* __restrict__ A, const unsigned short* __restrict__ B,
    const float* __restrict__ bias, float* __restrict__ C) {
  __shared__ unsigned short sA[128 * 32];
  __shared__ unsigned short sB[128 * 32];

  int bid = blockIdx.x;
  const int cpx = gridDim.x >> 3;
  bid = (bid & 7) * cpx + (bid >> 3);
  const int tileM = (bid >> 3) * 128;
  const int tileN = (bid & 7) * 128;

  const int t = threadIdx.x;
  const int lane = t & 63;
  const int wid = t >> 6;
  const int wm = wid >> 1, wn = wid & 1;
  const int lrow = lane & 15;
  const int lgrp = lane >> 4;

  f32x4 acc[4][4];
#pragma unroll
  for (int a = 0; a < 4; ++a)
#pragma unroll
    for (int b = 0; b < 4; ++b) acc[a][b] = (f32x4){0.f, 0.f, 0.f, 0.f};

  const int row0 = t >> 2;
  const int kk = (t & 3) * 8;
  const size_t abase = ((size_t)(tileM + row0)) * 1024 + kk;
  const size_t bbase = ((size_t)(tileN + row0)) * 1024 + kk;

  for (int k0 = 0; k0 < 1024; k0 += 32) {
#pragma unroll
    for (int c = 0; c < 2; ++c) {
      GLD16(A + abase + (size_t)c * 64 * 1024 + k0,
            (char*)sA + c * 4096 + t * 16);
      GLD16(B + bbase + (size_t)c * 64 * 1024 + k0,
            (char*)sB + c * 4096 + t * 16);
    }
    __syncthreads();

    bf16x8 af[4], bfr[4];
#pragma unroll
    for (int mi = 0; mi < 4; ++mi)
      af[mi] = *(const bf16x8*)&sA[(wm * 64 + mi * 16 + lrow) * 32 + lgrp * 8];
#pragma unroll
    for (int ni = 0; ni < 4; ++ni)
      bfr[ni] = *(const bf16x8*)&sB[(wn * 64 + ni * 16 + lrow) * 32 + lgrp * 8];
#pragma unroll
    for (int mi = 0; mi < 4; ++mi)
#pragma unroll
      for (int ni = 0; ni < 4; ++ni)
        acc[mi][ni] = __builtin_amdgcn_mfma_f32_16x16x32_bf16(
            af[mi], bfr[ni], acc[mi][ni], 0, 0, 0);
    __syncthreads();
  }

#pragma unroll
  for (int ni = 0; ni < 4; ++ni) {
    const int colc = tileN + wn * 64 + ni * 16 + lrow;
    const float bv = bias[colc];
#pragma unroll
    for (int mi = 0; mi < 4; ++mi) {
      const int row = tileM + wm * 64 + mi * 16 + lgrp * 4;
#pragma unroll
      for (int r = 0; r < 4; ++r)
        C[(size_t)(row + r) * 1024 + colc] = acc[mi][ni][r] + bv;
    }
  }
}

// ---------------------------------------------------------------------------
extern "C" void kernel_launch(void* const* d_in, const int* in_sizes, int n_in,
                              void* d_out, int out_size, void* d_ws,
                              size_t ws_size, hipStream_t stream) {
  const float* Q = (const float*)d_in[0];
  const float* K = (const float*)d_in[1];
  const float* V = (const float*)d_in[2];
  const int* mask = (const int*)d_in[3];
  const float* W = (const float*)d_in[4];
  const float* bias = (const float*)d_in[5];
  float* out = (float*)d_out;

  __bf16* X = (__bf16*)d_ws;  // 16384x1024 bf16 = 32 MB
  unsigned short* Wb =
      (unsigned short*)((char*)d_ws + (size_t)32 * 1024 * 1024);  // 2 MB

  hipLaunchKernelGGL(attn_kernel, dim3(8 * S_LEN / 16), dim3(256), 0, stream,
                     Q, K, V, mask, X);
  hipLaunchKernelGGL(wconv_kernel, dim3(1024), dim3(256), 0, stream, W, Wb);
  hipLaunchKernelGGL(gemm_kernel, dim3(1024), dim3(256), 0, stream,
                     (const unsigned short*)X, Wb, bias, out);
}

// Round 15
// 98.954 us; speedup vs baseline: 1.0035x; 1.0035x over previous
//
#include <hip/hip_runtime.h>
#include <stdint.h>

#define S_LEN 2048
#define EMB 1024

typedef __bf16 bf16x8 __attribute__((ext_vector_type(8)));
typedef __bf16 bf16x4 __attribute__((ext_vector_type(4)));
typedef float f32x4 __attribute__((ext_vector_type(4)));

__device__ __forceinline__ unsigned short f2bf(float f) {
  unsigned int b = __float_as_uint(f);
  b += 0x7FFFu + ((b >> 16) & 1u);
  return (unsigned short)(b >> 16);
}

__device__ __forceinline__ bf16x4 c4(float4 a) {
  bf16x4 r;
  r[0] = (__bf16)a.x; r[1] = (__bf16)a.y; r[2] = (__bf16)a.z; r[3] = (__bf16)a.w;
  return r;
}

#define GLD16(gp, lp)                                                          \
  __builtin_amdgcn_global_load_lds(                                            \
      (const __attribute__((address_space(1))) void*)(gp),                     \
      (__attribute__((address_space(3))) void*)(lp), 16, 0, 0)

// row-local swizzle for 2KB bf16 rows (R13-verified, both sides)
__device__ __forceinline__ int swz(int L) {
  return L ^ (((L >> 7) & 7) << 4);
}

// ---------------------------------------------------------------------------
// Kernel 1: per-(n,s) 16x16 head-Gram attention — line-exact reads at HIGH
// occupancy. Block = 256 thr / 4 positions (one per wave), 26 KB LDS ->
// 6 blocks/CU (75% occupancy ceiling). Phase 1: ALL of Q/K/V staged via
// perfectly-contiguous float4 loads (1KB/wave-instr, zero line waste),
// cvt->bf16 LDS (Q/K XOR-swizzled). Phase 2: R13-verified compute + R5
// scattered stores. Grid 4096 blocks (TLP does the overlap).
// ---------------------------------------------------------------------------
__global__ __launch_bounds__(256) void attn_kernel(
    const float* __restrict__ Q, const float* __restrict__ K,
    const float* __restrict__ V, const int* __restrict__ mask,
    __bf16* __restrict__ X) {
  __shared__ __bf16 Qb[4][1024];   // swizzled rows, 8 KB
  __shared__ __bf16 Kb[4][1024];   // swizzled rows, 8 KB
  __shared__ __bf16 Vb[4][1024];   // linear rows, 8 KB
  __shared__ __bf16 As[4][16][16]; // 2 KB

  const int t = threadIdx.x;
  const int lane = t & 63;
  const int wv = t >> 6;
  const int pos0 = blockIdx.x * 4;
  const int n = pos0 >> 11;  // uniform in block
  const int col = lane & 15;
  const int grp = lane >> 4;
  const int gc = grp & 1;

  const int4 mrow = *(const int4*)(mask + col * 16 + grp * 4);

  // ---- Phase 1: contiguous staging, 12 float4 loads/thread ----
  const int Lw = 8 * t;        // byte offset of this thread's 4 bf16 elems
  const int LwS = swz(Lw);
#pragma unroll
  for (int p = 0; p < 4; ++p) {
    const size_t base = (size_t)(pos0 + p) * EMB + t * 4;
    const float4 q4 = *(const float4*)(Q + base);
    const float4 k4 = *(const float4*)(K + base);
    const float4 v4 = *(const float4*)(V + base);
    *(bf16x4*)((char*)&Qb[p][0] + LwS) = c4(q4);
    *(bf16x4*)((char*)&Kb[p][0] + LwS) = c4(k4);
    *(bf16x4*)((char*)&Vb[p][0] + Lw) = c4(v4);
  }
  __syncthreads();

  // ---- Phase 2: wave wv computes position pos0+wv (R13-verified) ----
  const int s = (pos0 + wv) & 2047;
  const __bf16* qr = &Qb[wv][0];
  const __bf16* kr = &Kb[wv][0];
  const __bf16* vr = &Vb[wv][0];

  // QK^T fragments: elems col*64 + {0,32} + grp*8..+7 (bytes col*128+grp*16)
  const int L0 = col * 128 + grp * 16;
  const int L1 = L0 + 64;
  const bf16x8 qa0 = *(const bf16x8*)((const char*)qr + swz(L0));
  const bf16x8 qa1 = *(const bf16x8*)((const char*)qr + swz(L1));
  const bf16x8 kb0 = *(const bf16x8*)((const char*)kr + swz(L0));
  const bf16x8 kb1 = *(const bf16x8*)((const char*)kr + swz(L1));

  // E^T = K.Q^T (swapped): lane holds E[j=grp*4+r][i=col]
  f32x4 en = {0.f, 0.f, 0.f, 0.f};
  en = __builtin_amdgcn_mfma_f32_16x16x32_bf16(kb0, qa0, en, 0, 0, 0);
  en = __builtin_amdgcn_mfma_f32_16x16x32_bf16(kb1, qa1, en, 0, 0, 0);

  // mask + softmax over j
  float p[4];
  p[0] = (mrow.x == 0) ? -1e30f : en[0] * 0.125f;
  p[1] = (mrow.y == 0) ? -1e30f : en[1] * 0.125f;
  p[2] = (mrow.z == 0) ? -1e30f : en[2] * 0.125f;
  p[3] = (mrow.w == 0) ? -1e30f : en[3] * 0.125f;
  float mx = fmaxf(fmaxf(p[0], p[1]), fmaxf(p[2], p[3]));
  mx = fmaxf(mx, __shfl_xor(mx, 16));
  mx = fmaxf(mx, __shfl_xor(mx, 32));
  float ex[4], sm = 0.f;
#pragma unroll
  for (int r = 0; r < 4; ++r) {
    ex[r] = __expf(p[r] - mx);
    sm += ex[r];
  }
  sm += __shfl_xor(sm, 16);
  sm += __shfl_xor(sm, 32);
  const float inv = __builtin_amdgcn_rcpf(sm);
  bf16x4 aw;
#pragma unroll
  for (int r = 0; r < 4; ++r) aw[r] = (__bf16)(ex[r] * inv);
  *(bf16x4*)&As[wv][col][grp * 4] = aw;  // A[col][grp*4+r]

  // pa[e] = A[col][grp*8+e] for grp<2; zero-pad k>=16
  const bf16x8 pt = *(const bf16x8*)&As[wv][col][gc * 8];
  bf16x8 pa;
#pragma unroll
  for (int e = 0; e < 8; ++e) pa[e] = (grp < 2) ? pt[e] : (__bf16)0.f;

  // PV from LDS V + direct stores (R5-verified)
  const size_t xrow = (size_t)n * S_LEN + (size_t)col * 128 + (s >> 4);
  __bf16* xp = X + xrow * EMB + (size_t)((s & 15) * 64 + grp * 4);
#pragma unroll
  for (int c = 0; c < 4; ++c) {
    bf16x8 vf;
#pragma unroll
    for (int e = 0; e < 8; ++e)
      vf[e] = vr[(gc * 8 + e) * 64 + c * 16 + col];
    f32x4 o = {0.f, 0.f, 0.f, 0.f};
    o = __builtin_amdgcn_mfma_f32_16x16x32_bf16(vf, pa, o, 0, 0, 0);
    bf16x4 w;
#pragma unroll
    for (int r = 0; r < 4; ++r) w[r] = (__bf16)o[r];
    *(bf16x4*)(xp + c * 16) = w;
  }
}

// ---------------------------------------------------------------------------
// Kernel 2: W_out fp32 -> bf16 bits
// ---------------------------------------------------------------------------
__global__ __launch_bounds__(256) void wconv_kernel(
    const float* __restrict__ W, unsigned short* __restrict__ Wb) {
  const int idx = blockIdx.x * 256 + threadIdx.x;
  float4 w = *(const float4*)(W + (size_t)idx * 4);
  ushort4 o;
  o.x = f2bf(w.x);
  o.y = f2bf(w.y);
  o.z = f2bf(w.z);
  o.w = f2bf(w.w);
  *(ushort4*)(Wb + (size_t)idx * 4) = o;
}

// ---------------------------------------------------------------------------
// Kernel 3: C[16384][1024] = X[16384][1024] * W[1024][1024]^T + bias
// ---------------------------------------------------------------------------
__global__ __launch_bounds__(256) void gemm_kernel(
    const unsigned short* __restrict__ A, const unsigned short* __restrict__ B,
    const float* __restrict__ bias, float* __restrict__ C) {
  __shared__ unsigned short sA[128 * 32];
  __shared__ unsigned short sB[128 * 32];

  int bid = blockIdx.x;
  const int cpx = gridDim.x >> 3;
  bid = (bid & 7) * cpx + (bid >> 3);
  const int tileM = (bid >> 3) * 128;
  const int tileN = (bid & 7) * 128;

  const int t = threadIdx.x;
  const int lane = t & 63;
  const int wid = t >> 6;
  const int wm = wid >> 1, wn = wid & 1;
  const int lrow = lane & 15;
  const int lgrp = lane >> 4;

  f32x4 acc[4][4];
#pragma unroll
  for (int a = 0; a < 4; ++a)
#pragma unroll
    for (int b = 0; b < 4; ++b) acc[a][b] = (f32x4){0.f, 0.f, 0.f, 0.f};

  const int row0 = t >> 2;
  const int kk = (t & 3) * 8;
  const size_t abase = ((size_t)(tileM + row0)) * 1024 + kk;
  const size_t bbase = ((size_t)(tileN + row0)) * 1024 + kk;

  for (int k0 = 0; k0 < 1024; k0 += 32) {
#pragma unroll
    for (int c = 0; c < 2; ++c) {
      GLD16(A + abase + (size_t)c * 64 * 1024 + k0,
            (char*)sA + c * 4096 + t * 16);
      GLD16(B + bbase + (size_t)c * 64 * 1024 + k0,
            (char*)sB + c * 4096 + t * 16);
    }
    __syncthreads();

    bf16x8 af[4], bfr[4];
#pragma unroll
    for (int mi = 0; mi < 4; ++mi)
      af[mi] = *(const bf16x8*)&sA[(wm * 64 + mi * 16 + lrow) * 32 + lgrp * 8];
#pragma unroll
    for (int ni = 0; ni < 4; ++ni)
      bfr[ni] = *(const bf16x8*)&sB[(wn * 64 + ni * 16 + lrow) * 32 + lgrp * 8];
#pragma unroll
    for (int mi = 0; mi < 4; ++mi)
#pragma unroll
      for (int ni = 0; ni < 4; ++ni)
        acc[mi][ni] = __builtin_amdgcn_mfma_f32_16x16x32_bf16(
            af[mi], bfr[ni], acc[mi][ni], 0, 0, 0);
    __syncthreads();
  }

#pragma unroll
  for (int ni = 0; ni < 4; ++ni) {
    const int colc = tileN + wn * 64 + ni * 16 + lrow;
    const float bv = bias[colc];
#pragma unroll
    for (int mi = 0; mi < 4; ++mi) {
      const int row = tileM + wm * 64 + mi * 16 + lgrp * 4;
#pragma unroll
      for (int r = 0; r < 4; ++r)
        C[(size_t)(row + r) * 1024 + colc] = acc[mi][ni][r] + bv;
    }
  }
}

// ---------------------------------------------------------------------------
extern "C" void kernel_launch(void* const* d_in, const int* in_sizes, int n_in,
                              void* d_out, int out_size, void* d_ws,
                              size_t ws_size, hipStream_t stream) {
  const float* Q = (const float*)d_in[0];
  const float* K = (const float*)d_in[1];
  const float* V = (const float*)d_in[2];
  const int* mask = (const int*)d_in[3];
  const float* W = (const float*)d_in[4];
  const float* bias = (const float*)d_in[5];
  float* out = (float*)d_out;

  __bf16* X = (__bf16*)d_ws;  // 16384x1024 bf16 = 32 MB
  unsigned short* Wb =
      (unsigned short*)((char*)d_ws + (size_t)32 * 1024 * 1024);  // 2 MB

  hipLaunchKernelGGL(attn_kernel, dim3(8 * S_LEN / 4), dim3(256), 0, stream,
                     Q, K, V, mask, X);
  hipLaunchKernelGGL(wconv_kernel, dim3(1024), dim3(256), 0, stream, W, Wb);
  hipLaunchKernelGGL(gemm_kernel, dim3(1024), dim3(256), 0, stream,
                     (const unsigned short*)X, Wb, bias, out);
}